// Round 15
// baseline (511.107 us; speedup 1.0000x reference)
//
#include <hip/hip_runtime.h>

typedef unsigned short u16;
typedef __attribute__((ext_vector_type(8))) __bf16 bf16x8;
typedef __attribute__((ext_vector_type(16))) float f32x16;

__device__ __forceinline__ float bf2f(u16 u) {
  union { unsigned i; float f; } x; x.i = ((unsigned)u) << 16; return x.f;
}
__device__ __forceinline__ u16 f2bf(float f) {
  union { float f; unsigned i; } x; x.f = f;
  unsigned r = x.i + 0x7FFFu + ((x.i >> 16) & 1u);
  return (u16)(r >> 16);
}
__device__ __forceinline__ bf16x8 ld8(const u16* p) {
  union { int2 i2[2]; bf16x8 v; } u;
  u.i2[0] = *(const int2*)p;
  u.i2[1] = *(const int2*)(p + 4);
  return u.v;
}
__device__ __forceinline__ bf16x8 as_bf(int4 v) {
  union { int4 i; bf16x8 b; } u; u.i = v; return u.b;
}

// ---------------- prep: weight transform + NCHW->NHWC transpose (merged) ----------------
// f32 w[Cout][Cin][3][3] -> bf16 wT[kk][n_phys][64], kk = cc*taps + t (cc = 64-ch chunk).
// n-pairing: phys row (q*64 + f*32 + col) holds logical channel (q*64 + 2*col + f).
struct WJob { const float* src; u16* dst; int Cin, Cout, taps, NC, Cpad, special; };
struct WArgs {
  WJob j[16];
  const float *box_w, *ctr_w;
  const float *cls_b, *box_b, *ctr_b;
  float *bcls, *bbc;
  const float *tc3, *tc4, *tc5;
  u16 *tc3t, *tc4t, *tc5t;
};

__global__ __launch_bounds__(256) void prep_kernel(WArgs a) {
  if (blockIdx.y < 16) {
    WJob jb = a.j[blockIdx.y];
    int count = jb.taps * jb.NC * jb.Cpad * 64;
    for (int e = blockIdx.x * 256 + threadIdx.x; e < count; e += gridDim.x * 256) {
      int cw = e & 63;
      int r = e >> 6;
      int n = r % jb.Cpad;            // phys row
      int q = r / jb.Cpad;            // q = cc*taps + t
      int t = q % jb.taps;
      int cc = q / jb.taps;
      int ci = cc * 64 + cw;
      int nl = (n & ~63) + 2 * (n & 31) + ((n >> 5) & 1);   // logical out channel
      float v = 0.f;
      if (jb.special) {
        if (ci < jb.Cin) {
          if (nl < 4) v = a.box_w[((size_t)nl * jb.Cin + ci) * jb.taps + t];
          else if (nl == 4) v = a.ctr_w[(size_t)ci * jb.taps + t];
        }
      } else if (nl < jb.Cout && ci < jb.Cin) {
        v = jb.src[((size_t)nl * jb.Cin + ci) * jb.taps + t];
      }
      jb.dst[e] = f2bf(v);
    }
    if (blockIdx.y == 0 && blockIdx.x == 0) {
      int t = threadIdx.x;
      if (t < 128) a.bcls[t] = (t < 80) ? a.cls_b[t] : 0.f;
      else if (t < 192) {
        int n = t - 128;
        a.bbc[n] = (n < 4) ? a.box_b[n] : (n == 4 ? a.ctr_b[0] : 0.f);
      }
    }
  } else {
    // f32 NCHW -> bf16 NHWC for c3/c4/c5, grid-stride
    for (int gid = blockIdx.x * 256 + threadIdx.x; gid < 1056768; gid += gridDim.x * 256) {
      int g = gid;
      const float* in; u16* out; int C, HW;
      if (g < 524288) { in = a.tc3; out = a.tc3t; C = 64; HW = 4096; }
      else if (g < 851968) { g -= 524288; in = a.tc4; out = a.tc4t; C = 160; HW = 1024; }
      else { g -= 851968; in = a.tc5; out = a.tc5t; C = 400; HW = 256; }
      int CHW = C * HW;
      int b = g / CHW;
      int rem = g - b * CHW;
      int c = rem / HW;
      int pos = rem - c * HW;
      out[((size_t)b * HW + pos) * C + c] = f2bf(in[g]);
    }
  }
}

// ---------------- fused upsample-adds, int4-vectorized (8 ch/thread) ----------------
// l4n = l4 + up2(l5);  l3 += up2(l4) + up4(l5)
__global__ __launch_bounds__(256) void upadd2_kernel(u16* __restrict__ l3, u16* __restrict__ l4n,
                                                     const u16* __restrict__ l4,
                                                     const u16* __restrict__ l5) {
  int gid = blockIdx.x * 256 + threadIdx.x;
  if (gid < 65536) {
    int cg = (gid & 31) << 3;
    int m = gid >> 5;
    int b = m >> 10, pos = m & 1023;
    int y = pos >> 5, x = pos & 31;
    int sp = (b << 8) + ((y >> 1) << 4) + (x >> 1);
    union { int4 v; u16 s[8]; } A, B, O;
    A.v = *(const int4*)(l4 + (size_t)m * 256 + cg);
    B.v = *(const int4*)(l5 + (size_t)sp * 256 + cg);
#pragma unroll
    for (int i = 0; i < 8; ++i) O.s[i] = f2bf(bf2f(A.s[i]) + bf2f(B.s[i]));
    *(int4*)(l4n + (size_t)m * 256 + cg) = O.v;
  } else {
    int g2 = gid - 65536;
    int cg = (g2 & 31) << 3;
    int m = g2 >> 5;
    int b = m >> 12, pos = m & 4095;
    int y = pos >> 6, x = pos & 63;
    int sp2 = (b << 10) + ((y >> 1) << 5) + (x >> 1);
    int sp4 = (b << 8) + ((y >> 2) << 4) + (x >> 2);
    union { int4 v; u16 s[8]; } A, B, C2, O;
    A.v = *(const int4*)(l3 + (size_t)m * 256 + cg);
    B.v = *(const int4*)(l4 + (size_t)sp2 * 256 + cg);
    C2.v = *(const int4*)(l5 + (size_t)sp4 * 256 + cg);
#pragma unroll
    for (int i = 0; i < 8; ++i) O.s[i] = f2bf(bf2f(A.s[i]) + bf2f(B.s[i]) + bf2f(C2.s[i]));
    *(int4*)(l3 + (size_t)m * 256 + cg) = O.v;
  }
}

struct ConvP {
  const u16* src[2][3];
  const u16* wT[2][3];
  const float* bias[2][3];
  void* dst[2][3];
  int H[3], W[3], lgW[3], lgHW[3], pre[3], NC[3], Crow[3], locoff[3];
  int Cpad[2], Nvalid[2], choff[2], ny[2];
  int relu, direct;
};

#define APAD 68

// ---------------- lateral 1x1 conv: r9 kernel (proven, unchanged) ----------------
#define TAPX(RB) do {                                                          \
    if (kk + 1 < ktot) {                                                       \
      writeB((kk + 1) & 1, RB);                                                \
      if (kk + 3 < ktot) loadB(kk + 3, RB);                                    \
    }                                                                          \
    const u16* ar = As + hpbase * APAD + koffs;                                \
    const u16* br0 = Bs[kk & 1] + (lane & 31) * APAD + koffs;                  \
    const u16* br1 = br0 + 32 * APAD;                                          \
    _Pragma("unroll")                                                          \
    for (int ks = 0; ks < 4; ++ks) {                                           \
      bf16x8 af = ld8(ar + ks * 16);                                           \
      acc[0] = __builtin_amdgcn_mfma_f32_32x32x16_bf16(af, ld8(br0 + ks * 16), acc[0], 0, 0, 0); \
      acc[1] = __builtin_amdgcn_mfma_f32_32x32x16_bf16(af, ld8(br1 + ks * 16), acc[1], 0, 0, 0); \
    }                                                                          \
    __syncthreads();                                                           \
    ++kk; ++cc;                                                                \
    if (cc < NCv) {                                                            \
      writeA(rA);                                                              \
      if (cc + 1 < NCv) loadA(cc + 1, rA);                                     \
      __syncthreads();                                                         \
    }                                                                          \
  } while (0)

__global__ __launch_bounds__(256, 3) void conv1_kernel(ConvP p) {
  constexpr int HALO_W = 8;
  constexpr int NA = 16 * 8 * 8;
  constexpr int NSLOT = 4;
  __shared__ u16 As[128 * APAD];
  __shared__ u16 Bs[2][64 * APAD];
  const int tid = threadIdx.x;
  const int br = blockIdx.z;
  if (blockIdx.y >= p.ny[br]) return;
  const int bx = blockIdx.x;
  const int lv = (bx >= p.pre[1]) + (bx >= p.pre[2]);
  const u16* __restrict__ src = p.src[br][lv];
  const u16* __restrict__ wT = p.wT[br][lv];
  const float* bias = p.bias[br][lv];
  void* dstv = p.dst[br][lv];
  const int H = p.H[lv], W = p.W[lv];
  const int lgWv = p.lgW[lv], lgHWv = p.lgHW[lv];
  const int NCv = p.NC[lv], Crow = p.Crow[lv];
  const int Cpadv = p.Cpad[br];
  const int ktot = NCv;
  const int nt = blockIdx.y * 64;
  const int wave = tid >> 6, lane = tid & 63;

  const int pidx = bx - p.pre[lv];
  const int lgppb = lgHWv - 7;
  const int lgnpx = lgWv - 3;
  const int batch = pidx >> lgppb;
  const int pp = pidx & ((1 << lgppb) - 1);
  const int py0 = (pp >> lgnpx) << 4;
  const int px0 = (pp & ((1 << lgnpx) - 1)) << 3;
  const size_t srcb = (size_t)batch * (1 << lgHWv) * Crow;

  f32x16 acc[2];
#pragma unroll
  for (int i = 0; i < 16; ++i) { acc[0][i] = 0.f; acc[1][i] = 0.f; }

  const int ml = wave * 32 + (lane & 31);
  const int my = ml >> 3, mx = ml & 7;
  const int koffs = (lane >> 5) << 3;
  const int hpbase = my * HALO_W + mx;

  int4 rA[NSLOT];
  int4 rB0[2], rB1[2];

  auto loadA = [&](int cc2, int4* r) {
    int kb = cc2 << 6;
#pragma unroll
    for (int s = 0; s < NSLOT; ++s) {
      int idx = s * 256 + tid;
      int4 v = make_int4(0, 0, 0, 0);
      int pos = idx >> 3, part = idx & 7;
      int hy = pos >> 3, hx = pos & 7;
      int gy = py0 + hy, gx = px0 + hx;
      int ch = kb + (part << 3);
      if ((unsigned)gy < (unsigned)H && (unsigned)gx < (unsigned)W && ch < Crow)
        v = *(const int4*)(src + srcb + (size_t)((gy << lgWv) + gx) * Crow + ch);
      r[s] = v;
    }
  };
  auto writeA = [&](const int4* r) {
#pragma unroll
    for (int s = 0; s < NSLOT; ++s) {
      int idx = s * 256 + tid;
      int pos = idx >> 3, part = idx & 7;
      u16* d = As + pos * APAD + (part << 3);
      *(int2*)d = make_int2(r[s].x, r[s].y);
      *(int2*)(d + 4) = make_int2(r[s].z, r[s].w);
    }
  };
  auto loadB = [&](int j, int4* r) {
    const u16* wsrc = wT + (((size_t)j * Cpadv + nt) << 6);
    r[0] = *(const int4*)(wsrc + ((tid >> 3) << 6) + ((tid & 7) << 3));
    r[1] = *(const int4*)(wsrc + (((tid >> 3) + 32) << 6) + ((tid & 7) << 3));
  };
  auto writeB = [&](int bufi, const int4* r) {
    u16* bb = Bs[bufi];
    u16* d0 = bb + (tid >> 3) * APAD + ((tid & 7) << 3);
    u16* d1 = bb + ((tid >> 3) + 32) * APAD + ((tid & 7) << 3);
    *(int2*)d0 = make_int2(r[0].x, r[0].y);
    *(int2*)(d0 + 4) = make_int2(r[0].z, r[0].w);
    *(int2*)d1 = make_int2(r[1].x, r[1].y);
    *(int2*)(d1 + 4) = make_int2(r[1].z, r[1].w);
  };

  loadA(0, rA);
  loadB(0, rB0);
  if (ktot > 1) loadB(1, rB1);
  writeA(rA);
  writeB(0, rB0);
  if (ktot > 2) loadB(2, rB0);
  if (NCv > 1) loadA(1, rA);
  __syncthreads();

  int kk = 0, cc = 0;
  while (true) {
    TAPX(rB1);
    if (kk >= ktot) break;
    TAPX(rB0);
    if (kk >= ktot) break;
  }

  const int col = lane & 31;
  const int rbs = 4 * (lane >> 5);
  const float bv0 = bias[nt + 2 * col];
  const float bv1 = bias[nt + 2 * col + 1];
#pragma unroll
  for (int r = 0; r < 16; ++r) {
    int m2 = wave * 32 + rbs + (r & 3) + 8 * (r >> 2);
    int posi = ((py0 + (m2 >> 3)) << lgWv) + px0 + (m2 & 7);
    float v0 = acc[0][r] + bv0;
    float v1 = acc[1][r] + bv1;
    unsigned pk = (unsigned)f2bf(v0) | ((unsigned)f2bf(v1) << 16);
    *(unsigned*)((u16*)dstv + ((size_t)(batch << lgHWv) + posi) * 256 + nt + 2 * col) = pk;
  }
}

// ---------------- 3x3 conv: 3-slot B-ring + b128 LDS, APAD9=72, NO swizzle ----------------
// Stride 72 u16 = 144 B = 36 banks == 4-bank (one 16B-group) natural rotation per row:
// bank-start = 4*(row + g) mod 32 -> distinct across any 8 consecutive rows. Adding an
// explicit swizzle on top CANCELS this (r13's exact-2x conflict bug). Plain layout,
// single ds_read_b128 / ds_write_b128 per fragment: 12 LDS reads/tap/wave vs 24 b64.
#define APAD9 72

#define TAP9(T, S) do {                                                        \
    constexpr int hpo_ = ((T) / 3 - 1) * 10 + ((T) % 3 - 1);                   \
    const u16* ar = As + (hpbase + hpo_) * APAD9 + koffs;                      \
    const u16* br0 = Bs[S] + (lane & 31) * APAD9 + koffs;                      \
    const u16* br1 = br0 + 32 * APAD9;                                         \
    _Pragma("unroll")                                                          \
    for (int ks = 0; ks < 4; ++ks) {                                           \
      bf16x8 af = as_bf(*(const int4*)(ar + ks * 16));                         \
      acc[0] = __builtin_amdgcn_mfma_f32_32x32x16_bf16(af, as_bf(*(const int4*)(br0 + ks * 16)), acc[0], 0, 0, 0); \
      acc[1] = __builtin_amdgcn_mfma_f32_32x32x16_bf16(af, as_bf(*(const int4*)(br1 + ks * 16)), acc[1], 0, 0, 0); \
    }                                                                          \
  } while (0)

__global__ __launch_bounds__(256, 3) void conv9_kernel(ConvP p) {
  constexpr int HALO_W = 10;
  constexpr int NA = 18 * 10 * 8;            // 1440
  constexpr int NSLOT = 6;
  __shared__ __align__(16) u16 As[180 * APAD9];   // 25.3 KB
  __shared__ __align__(16) u16 Bs[3][64 * APAD9]; // 27.0 KB -> 52.3 KB total, 3 blocks/CU
  const int tid = threadIdx.x;
  const int br = blockIdx.z;
  if (blockIdx.y >= p.ny[br]) return;
  const int bx = blockIdx.x;
  const int lv = (bx >= p.pre[1]) + (bx >= p.pre[2]);
  const u16* __restrict__ src = p.src[br][lv];
  const u16* __restrict__ wT = p.wT[br][lv];
  const float* bias = p.bias[br][lv];
  void* dstv = p.dst[br][lv];
  const int H = p.H[lv], W = p.W[lv];
  const int lgWv = p.lgW[lv], lgHWv = p.lgHW[lv];
  const int Crow = p.Crow[lv];
  const int Cpadv = p.Cpad[br];
  const int nt = blockIdx.y * 64;
  const int wave = tid >> 6, lane = tid & 63;

  const int pidx = bx - p.pre[lv];
  const int lgppb = lgHWv - 7;
  const int lgnpx = lgWv - 3;
  const int batch = pidx >> lgppb;
  const int pp = pidx & ((1 << lgppb) - 1);
  const int py0 = (pp >> lgnpx) << 4;
  const int px0 = (pp & ((1 << lgnpx) - 1)) << 3;
  const size_t srcb = (size_t)batch * (1 << lgHWv) * Crow;

  f32x16 acc[2];
#pragma unroll
  for (int i = 0; i < 16; ++i) { acc[0][i] = 0.f; acc[1][i] = 0.f; }

  const int ml = wave * 32 + (lane & 31);
  const int my = ml >> 3, mx = ml & 7;
  const int koffs = (lane >> 5) << 3;
  const int hpbase = (my + 1) * HALO_W + (mx + 1);

  int4 rA[NSLOT];
  int4 rB[6];                                // 3 slots x 2 int4, constant-indexed

  auto loadA = [&](int cc2, int4* r) {
    int kb = cc2 << 6;
#pragma unroll
    for (int s = 0; s < NSLOT; ++s) {
      int idx = s * 256 + tid;
      int4 v = make_int4(0, 0, 0, 0);
      if (idx < NA) {
        int pos = idx >> 3, part = idx & 7;
        int hy = pos / HALO_W, hx = pos - hy * HALO_W;
        int gy = py0 + hy - 1, gx = px0 + hx - 1;
        int ch = kb + (part << 3);
        if ((unsigned)gy < (unsigned)H && (unsigned)gx < (unsigned)W && ch < Crow)
          v = *(const int4*)(src + srcb + (size_t)((gy << lgWv) + gx) * Crow + ch);
      }
      r[s] = v;
    }
  };
  auto writeA = [&](const int4* r) {
#pragma unroll
    for (int s = 0; s < NSLOT; ++s) {
      int idx = s * 256 + tid;
      if (idx < NA) {
        int pos = idx >> 3, part = idx & 7;
        *(int4*)(As + pos * APAD9 + (part << 3)) = r[s];
      }
    }
  };
  auto loadB3 = [&](int j, int4* r) {        // loads kk = j, j+1, j+2
#pragma unroll
    for (int s = 0; s < 3; ++s) {
      const u16* wsrc = wT + (((size_t)(j + s) * Cpadv + nt) << 6);
      r[2 * s] = *(const int4*)(wsrc + ((tid >> 3) << 6) + ((tid & 7) << 3));
      r[2 * s + 1] = *(const int4*)(wsrc + (((tid >> 3) + 32) << 6) + ((tid & 7) << 3));
    }
  };
  auto writeB3 = [&](const int4* r) {        // stores slots 0,1,2
    const int o0 = (tid >> 3) * APAD9 + ((tid & 7) << 3);
    const int o1 = o0 + 32 * APAD9;
#pragma unroll
    for (int s = 0; s < 3; ++s) {
      *(int4*)(Bs[s] + o0) = r[2 * s];
      *(int4*)(Bs[s] + o1) = r[2 * s + 1];
    }
  };

  // prologue: slots <- kk 0..2; rB <- kk 3..5; As <- chunk0; rA <- chunk1
  loadA(0, rA);
  loadB3(0, rB);
  writeA(rA);
  writeB3(rB);
  loadB3(3, rB);
  loadA(1, rA);
  __syncthreads();

  for (int cc = 0; cc < 4; ++cc) {
    TAP9(0, 0); TAP9(1, 1); TAP9(2, 2);
    __syncthreads();                         // vmcnt drain: rB loads are 3 taps old
    writeB3(rB);                             // slots <- 9cc+3..5
    __syncthreads();
    loadB3(cc * 9 + 6, rB);
    TAP9(3, 0); TAP9(4, 1); TAP9(5, 2);
    __syncthreads();
    writeB3(rB);                             // slots <- 9cc+6..8
    __syncthreads();
    if (cc * 9 + 9 < 36) loadB3(cc * 9 + 9, rB);
    TAP9(6, 0); TAP9(7, 1); TAP9(8, 2);
    __syncthreads();
    if (cc < 3) {
      writeB3(rB);                           // slots <- 9(cc+1)+0..2
      writeA(rA);                            // As <- chunk cc+1
      __syncthreads();
      loadB3(cc * 9 + 12, rB);
      if (cc < 2) loadA(cc + 2, rA);
    }
  }

  // epilogue: C/D layout col=lane&31, row=(reg&3)+8*(reg>>2)+4*(lane>>5).
  // acc[f] col c = logical channel nt + 2c + f (pairN weights) -> packed dword store.
  const int col = lane & 31;
  const int rbs = 4 * (lane >> 5);
  const int nbase = nt + 2 * col;
  const float bv0 = bias[nbase];
  const float bv1 = bias[nbase + 1];
#pragma unroll
  for (int r = 0; r < 16; ++r) {
    int m2 = wave * 32 + rbs + (r & 3) + 8 * (r >> 2);
    int posi = ((py0 + (m2 >> 3)) << lgWv) + px0 + (m2 & 7);
    float v0 = acc[0][r] + bv0;
    float v1 = acc[1][r] + bv1;
    if (p.relu) { v0 = fmaxf(v0, 0.f); v1 = fmaxf(v1, 0.f); }
    if (!p.direct) {
      unsigned pk = (unsigned)f2bf(v0) | ((unsigned)f2bf(v1) << 16);
      *(unsigned*)((u16*)dstv + ((size_t)(batch << lgHWv) + posi) * 256 + nbase) = pk;
    } else {
      float* dd = (float*)dstv + ((size_t)(batch * 5376 + p.locoff[lv] + posi)) * 85 + p.choff[br];
      if (nbase < p.Nvalid[br]) dd[nbase] = v0;
      if (nbase + 1 < p.Nvalid[br]) dd[nbase + 1] = v1;
    }
  }
}

// ---------------- host ----------------
extern "C" void kernel_launch(void* const* d_in, const int* in_sizes, int n_in,
                              void* d_out, int out_size, void* d_ws, size_t ws_size,
                              hipStream_t stream) {
  (void)in_sizes; (void)n_in; (void)out_size; (void)ws_size;
  const float* c3 = (const float*)d_in[0];
  const float* c4 = (const float*)d_in[1];
  const float* c5 = (const float*)d_in[2];
  const float* lat_w[3] = {(const float*)d_in[3], (const float*)d_in[7], (const float*)d_in[11]};
  const float* lat_b[3] = {(const float*)d_in[4], (const float*)d_in[8], (const float*)d_in[12]};
  const float* out_w[3] = {(const float*)d_in[5], (const float*)d_in[9], (const float*)d_in[13]};
  const float* out_b[3] = {(const float*)d_in[6], (const float*)d_in[10], (const float*)d_in[14]};
  const float* scw = (const float*)d_in[15];
  const float* scb = (const float*)d_in[16];
  const float* sbw = (const float*)d_in[17];
  const float* sbb = (const float*)d_in[18];
  const float* clsw = (const float*)d_in[19];
  const float* clsb = (const float*)d_in[20];
  const float* boxw = (const float*)d_in[21];
  const float* boxb = (const float*)d_in[22];
  const float* ctrw = (const float*)d_in[23];
  const float* ctrb = (const float*)d_in[24];
  float* out = (float*)d_out;
  u16* ws = (u16*)d_ws;

  size_t o = 0;
  auto alloc = [&](size_t n) { size_t r = o; o += (n + 127) & ~(size_t)127; return ws + r; };

  u16* c3t = alloc(524288);
  u16* c4t = alloc(327680);
  u16* c5t = alloc(204800);
  u16* l3 = alloc(2097152);
  u16* l4 = alloc(524288);
  u16* l4n = alloc(524288);
  u16* l5 = alloc(131072);
  u16* p3 = alloc(2097152);
  u16* p4 = alloc(524288);
  u16* p5 = alloc(131072);
  const size_t hsz[3] = {2097152, 524288, 131072};
  u16 *hc[2][3], *hb[2][3];
  for (int ab = 0; ab < 2; ++ab)
    for (int lvv = 0; lvv < 3; ++lvv) { hc[ab][lvv] = alloc(hsz[lvv]); hb[ab][lvv] = alloc(hsz[lvv]); }
  const int latCin[3] = {64, 160, 400};
  const int latNC[3] = {1, 3, 7};
  u16* wl[3]; for (int i = 0; i < 3; ++i) wl[i] = alloc((size_t)latNC[i] * 256 * 64);
  u16* wo[3]; for (int i = 0; i < 3; ++i) wo[i] = alloc(589824);
  u16* wsc[4]; for (int i = 0; i < 4; ++i) wsc[i] = alloc(589824);
  u16* wsb[4]; for (int i = 0; i < 4; ++i) wsb[i] = alloc(589824);
  u16* wcls = alloc(294912);
  u16* wbc = alloc(147456);
  float* bcls = (float*)alloc(256);
  float* bbc = (float*)alloc(128);
  alloc(2048);  // guard

  // ---- prep: weight transforms + input transpose (merged) ----
  WArgs wa;
  int ji = 0;
  for (int i = 0; i < 3; ++i) wa.j[ji++] = WJob{lat_w[i], wl[i], latCin[i], 256, 1, latNC[i], 256, 0};
  for (int i = 0; i < 3; ++i) wa.j[ji++] = WJob{out_w[i], wo[i], 256, 256, 9, 4, 256, 0};
  for (int i = 0; i < 4; ++i) wa.j[ji++] = WJob{scw + (size_t)i * 589824, wsc[i], 256, 256, 9, 4, 256, 0};
  for (int i = 0; i < 4; ++i) wa.j[ji++] = WJob{sbw + (size_t)i * 589824, wsb[i], 256, 256, 9, 4, 256, 0};
  wa.j[ji++] = WJob{clsw, wcls, 256, 80, 9, 4, 128, 0};
  wa.j[ji++] = WJob{nullptr, wbc, 256, 5, 9, 4, 64, 1};
  wa.box_w = boxw; wa.ctr_w = ctrw;
  wa.cls_b = clsb; wa.box_b = boxb; wa.ctr_b = ctrb; wa.bcls = bcls; wa.bbc = bbc;
  wa.tc3 = c3; wa.tc4 = c4; wa.tc5 = c5;
  wa.tc3t = c3t; wa.tc4t = c4t; wa.tc5t = c5t;
  prep_kernel<<<dim3(256, 17), dim3(256), 0, stream>>>(wa);

  const int Hs[3] = {64, 32, 16};
  const int lgWs[3] = {6, 5, 4}, lgHWs[3] = {12, 10, 8};
  auto setLv = [&](ConvP& p, int i, int lvv) {
    p.H[i] = Hs[lvv]; p.W[i] = Hs[lvv]; p.lgW[i] = lgWs[lvv]; p.lgHW[i] = lgHWs[lvv];
  };

  // ---- lateral 1x1 convs (all levels fused) ----
  {
    ConvP p{};
    const u16* srcs[3] = {c3t, c4t, c5t};
    u16* dsts[3] = {l3, l4, l5};
    for (int i = 0; i < 3; ++i) {
      p.src[0][i] = srcs[i]; p.wT[0][i] = wl[i]; p.bias[0][i] = lat_b[i]; p.dst[0][i] = dsts[i];
      setLv(p, i, i);
      p.NC[i] = latNC[i]; p.Crow[i] = latCin[i]; p.locoff[i] = 0;
    }
    p.pre[0] = 0; p.pre[1] = 64; p.pre[2] = 80;
    p.Cpad[0] = 256; p.Nvalid[0] = 0; p.choff[0] = 0; p.ny[0] = 4;
    p.relu = 0; p.direct = 0;
    conv1_kernel<<<dim3(84, 4, 1), dim3(256), 0, stream>>>(p);
  }

  // ---- fused upsample-adds (vectorized) ----
  upadd2_kernel<<<dim3(1280), dim3(256), 0, stream>>>(l3, l4n, l4, l5);

  // ---- FPN out convs (all levels fused) ----
  {
    ConvP p{};
    const u16* srcs[3] = {l3, l4n, l5};
    u16* dsts[3] = {p3, p4, p5};
    for (int i = 0; i < 3; ++i) {
      p.src[0][i] = srcs[i]; p.wT[0][i] = wo[i]; p.bias[0][i] = out_b[i]; p.dst[0][i] = dsts[i];
      setLv(p, i, i);
      p.NC[i] = 4; p.Crow[i] = 256; p.locoff[i] = 0;
    }
    p.pre[0] = 0; p.pre[1] = 64; p.pre[2] = 80;
    p.Cpad[0] = 256; p.Nvalid[0] = 0; p.choff[0] = 0; p.ny[0] = 4;
    p.relu = 0; p.direct = 0;
    conv9_kernel<<<dim3(84, 4, 1), dim3(256), 0, stream>>>(p);
  }

  // ---- stem layers: all levels + both branches fused per layer ----
  u16* pin[3] = {p3, p4, p5};
  for (int i = 0; i < 4; ++i) {
    ConvP p{};
    int di = i & 1;
    for (int lvv = 0; lvv < 3; ++lvv) {
      const u16 *s0, *s1;
      if (i == 0) { s0 = pin[lvv]; s1 = pin[lvv]; }
      else { int si = (i - 1) & 1; s0 = hc[si][lvv]; s1 = hb[si][lvv]; }
      p.src[0][lvv] = s0; p.src[1][lvv] = s1;
      p.wT[0][lvv] = wsc[i]; p.wT[1][lvv] = wsb[i];
      p.bias[0][lvv] = scb + i * 256; p.bias[1][lvv] = sbb + i * 256;
      p.dst[0][lvv] = hc[di][lvv]; p.dst[1][lvv] = hb[di][lvv];
      setLv(p, lvv, lvv);
      p.NC[lvv] = 4; p.Crow[lvv] = 256; p.locoff[lvv] = 0;
    }
    p.pre[0] = 0; p.pre[1] = 64; p.pre[2] = 80;
    p.Cpad[0] = 256; p.Cpad[1] = 256;
    p.Nvalid[0] = 0; p.Nvalid[1] = 0; p.choff[0] = 0; p.choff[1] = 0;
    p.ny[0] = 4; p.ny[1] = 4;
    p.relu = 1; p.direct = 0;
    conv9_kernel<<<dim3(84, 4, 2), dim3(256), 0, stream>>>(p);
  }

  // ---- fused finals: z=0 cls (80ch), z=1 box+ctr (5ch), f32 (B,5376,85) ----
  {
    const int locoffs[3] = {0, 4096, 5120};
    ConvP p{};
    for (int lvv = 0; lvv < 3; ++lvv) {
      p.src[0][lvv] = hc[1][lvv]; p.wT[0][lvv] = wcls; p.bias[0][lvv] = bcls; p.dst[0][lvv] = out;
      p.src[1][lvv] = hb[1][lvv]; p.wT[1][lvv] = wbc; p.bias[1][lvv] = bbc; p.dst[1][lvv] = out;
      setLv(p, lvv, lvv);
      p.NC[lvv] = 4; p.Crow[lvv] = 256; p.locoff[lvv] = locoffs[lvv];
    }
    p.pre[0] = 0; p.pre[1] = 64; p.pre[2] = 80;
    p.Cpad[0] = 128; p.Cpad[1] = 64;
    p.Nvalid[0] = 80; p.Nvalid[1] = 5;
    p.choff[0] = 0; p.choff[1] = 80;
    p.ny[0] = 2; p.ny[1] = 1;
    p.relu = 0; p.direct = 1;
    conv9_kernel<<<dim3(84, 2, 2), dim3(256), 0, stream>>>(p);
  }
}

// Round 16
// 353.553 us; speedup vs baseline: 1.4456x; 1.4456x over previous
//
#include <hip/hip_runtime.h>

typedef unsigned short u16;
typedef __attribute__((ext_vector_type(8))) __bf16 bf16x8;
typedef __attribute__((ext_vector_type(16))) float f32x16;

__device__ __forceinline__ float bf2f(u16 u) {
  union { unsigned i; float f; } x; x.i = ((unsigned)u) << 16; return x.f;
}
__device__ __forceinline__ u16 f2bf(float f) {
  union { float f; unsigned i; } x; x.f = f;
  unsigned r = x.i + 0x7FFFu + ((x.i >> 16) & 1u);
  return (u16)(r >> 16);
}
__device__ __forceinline__ bf16x8 ld8(const u16* p) {
  union { int2 i2[2]; bf16x8 v; } u;
  u.i2[0] = *(const int2*)p;
  u.i2[1] = *(const int2*)(p + 4);
  return u.v;
}

// ---------------- prep: weight transform + NCHW->NHWC transpose (merged) ----------------
// f32 w[Cout][Cin][3][3] -> bf16 wT[kk][n_phys][64], kk = cc*taps + t (cc = 64-ch chunk).
// n-pairing: phys row (q*64 + f*32 + col) holds logical channel (q*64 + 2*col + f).
struct WJob { const float* src; u16* dst; int Cin, Cout, taps, NC, Cpad, special; };
struct WArgs {
  WJob j[16];
  const float *box_w, *ctr_w;
  const float *cls_b, *box_b, *ctr_b;
  float *bcls, *bbc;
  const float *tc3, *tc4, *tc5;
  u16 *tc3t, *tc4t, *tc5t;
};

__global__ __launch_bounds__(256) void prep_kernel(WArgs a) {
  if (blockIdx.y < 16) {
    WJob jb = a.j[blockIdx.y];
    int count = jb.taps * jb.NC * jb.Cpad * 64;
    for (int e = blockIdx.x * 256 + threadIdx.x; e < count; e += gridDim.x * 256) {
      int cw = e & 63;
      int r = e >> 6;
      int n = r % jb.Cpad;            // phys row
      int q = r / jb.Cpad;            // q = cc*taps + t
      int t = q % jb.taps;
      int cc = q / jb.taps;
      int ci = cc * 64 + cw;
      int nl = (n & ~63) + 2 * (n & 31) + ((n >> 5) & 1);   // logical out channel
      float v = 0.f;
      if (jb.special) {
        if (ci < jb.Cin) {
          if (nl < 4) v = a.box_w[((size_t)nl * jb.Cin + ci) * jb.taps + t];
          else if (nl == 4) v = a.ctr_w[(size_t)ci * jb.taps + t];
        }
      } else if (nl < jb.Cout && ci < jb.Cin) {
        v = jb.src[((size_t)nl * jb.Cin + ci) * jb.taps + t];
      }
      jb.dst[e] = f2bf(v);
    }
    if (blockIdx.y == 0 && blockIdx.x == 0) {
      int t = threadIdx.x;
      if (t < 128) a.bcls[t] = (t < 80) ? a.cls_b[t] : 0.f;
      else if (t < 192) {
        int n = t - 128;
        a.bbc[n] = (n < 4) ? a.box_b[n] : (n == 4 ? a.ctr_b[0] : 0.f);
      }
    }
  } else {
    // f32 NCHW -> bf16 NHWC for c3/c4/c5, grid-stride
    for (int gid = blockIdx.x * 256 + threadIdx.x; gid < 1056768; gid += gridDim.x * 256) {
      int g = gid;
      const float* in; u16* out; int C, HW;
      if (g < 524288) { in = a.tc3; out = a.tc3t; C = 64; HW = 4096; }
      else if (g < 851968) { g -= 524288; in = a.tc4; out = a.tc4t; C = 160; HW = 1024; }
      else { g -= 851968; in = a.tc5; out = a.tc5t; C = 400; HW = 256; }
      int CHW = C * HW;
      int b = g / CHW;
      int rem = g - b * CHW;
      int c = rem / HW;
      int pos = rem - c * HW;
      out[((size_t)b * HW + pos) * C + c] = f2bf(in[g]);
    }
  }
}

// ---------------- fused upsample-adds, int4-vectorized (8 ch/thread) ----------------
// l4n = l4 + up2(l5);  l3 += up2(l4) + up4(l5)
__global__ __launch_bounds__(256) void upadd2_kernel(u16* __restrict__ l3, u16* __restrict__ l4n,
                                                     const u16* __restrict__ l4,
                                                     const u16* __restrict__ l5) {
  int gid = blockIdx.x * 256 + threadIdx.x;
  if (gid < 65536) {
    int cg = (gid & 31) << 3;
    int m = gid >> 5;
    int b = m >> 10, pos = m & 1023;
    int y = pos >> 5, x = pos & 31;
    int sp = (b << 8) + ((y >> 1) << 4) + (x >> 1);
    union { int4 v; u16 s[8]; } A, B, O;
    A.v = *(const int4*)(l4 + (size_t)m * 256 + cg);
    B.v = *(const int4*)(l5 + (size_t)sp * 256 + cg);
#pragma unroll
    for (int i = 0; i < 8; ++i) O.s[i] = f2bf(bf2f(A.s[i]) + bf2f(B.s[i]));
    *(int4*)(l4n + (size_t)m * 256 + cg) = O.v;
  } else {
    int g2 = gid - 65536;
    int cg = (g2 & 31) << 3;
    int m = g2 >> 5;
    int b = m >> 12, pos = m & 4095;
    int y = pos >> 6, x = pos & 63;
    int sp2 = (b << 10) + ((y >> 1) << 5) + (x >> 1);
    int sp4 = (b << 8) + ((y >> 2) << 4) + (x >> 2);
    union { int4 v; u16 s[8]; } A, B, C2, O;
    A.v = *(const int4*)(l3 + (size_t)m * 256 + cg);
    B.v = *(const int4*)(l4 + (size_t)sp2 * 256 + cg);
    C2.v = *(const int4*)(l5 + (size_t)sp4 * 256 + cg);
#pragma unroll
    for (int i = 0; i < 8; ++i) O.s[i] = f2bf(bf2f(A.s[i]) + bf2f(B.s[i]) + bf2f(C2.s[i]));
    *(int4*)(l3 + (size_t)m * 256 + cg) = O.v;
  }
}

struct ConvP {
  const u16* src[2][3];
  const u16* wT[2][3];
  const float* bias[2][3];
  void* dst[2][3];
  int H[3], W[3], lgW[3], lgHW[3], pre[3], NC[3], Crow[3], locoff[3];
  int Cpad[2], Nvalid[2], choff[2], ny[2];
  int relu, direct;
};

#define APAD 68

// ---------------- lateral 1x1 conv: r9 kernel (proven) ----------------
#define TAPX(RB) do {                                                          \
    if (kk + 1 < ktot) {                                                       \
      writeB((kk + 1) & 1, RB);                                                \
      if (kk + 3 < ktot) loadB(kk + 3, RB);                                    \
    }                                                                          \
    const u16* ar = As + hpbase * APAD + koffs;                                \
    const u16* br0 = Bs[kk & 1] + (lane & 31) * APAD + koffs;                  \
    const u16* br1 = br0 + 32 * APAD;                                          \
    _Pragma("unroll")                                                          \
    for (int ks = 0; ks < 4; ++ks) {                                           \
      bf16x8 af = ld8(ar + ks * 16);                                           \
      acc[0] = __builtin_amdgcn_mfma_f32_32x32x16_bf16(af, ld8(br0 + ks * 16), acc[0], 0, 0, 0); \
      acc[1] = __builtin_amdgcn_mfma_f32_32x32x16_bf16(af, ld8(br1 + ks * 16), acc[1], 0, 0, 0); \
    }                                                                          \
    __syncthreads();                                                           \
    ++kk; ++cc;                                                                \
    if (cc < NCv) {                                                            \
      writeA(rA);                                                              \
      if (cc + 1 < NCv) loadA(cc + 1, rA);                                     \
      __syncthreads();                                                         \
    }                                                                          \
  } while (0)

__global__ __launch_bounds__(256, 3) void conv1_kernel(ConvP p) {
  constexpr int HALO_W = 8;
  constexpr int NA = 16 * 8 * 8;
  constexpr int NSLOT = 4;
  __shared__ u16 As[128 * APAD];
  __shared__ u16 Bs[2][64 * APAD];
  const int tid = threadIdx.x;
  const int br = blockIdx.z;
  if (blockIdx.y >= p.ny[br]) return;
  const int bx = blockIdx.x;
  const int lv = (bx >= p.pre[1]) + (bx >= p.pre[2]);
  const u16* __restrict__ src = p.src[br][lv];
  const u16* __restrict__ wT = p.wT[br][lv];
  const float* bias = p.bias[br][lv];
  void* dstv = p.dst[br][lv];
  const int H = p.H[lv], W = p.W[lv];
  const int lgWv = p.lgW[lv], lgHWv = p.lgHW[lv];
  const int NCv = p.NC[lv], Crow = p.Crow[lv];
  const int Cpadv = p.Cpad[br];
  const int ktot = NCv;
  const int nt = blockIdx.y * 64;
  const int wave = tid >> 6, lane = tid & 63;

  const int pidx = bx - p.pre[lv];
  const int lgppb = lgHWv - 7;
  const int lgnpx = lgWv - 3;
  const int batch = pidx >> lgppb;
  const int pp = pidx & ((1 << lgppb) - 1);
  const int py0 = (pp >> lgnpx) << 4;
  const int px0 = (pp & ((1 << lgnpx) - 1)) << 3;
  const size_t srcb = (size_t)batch * (1 << lgHWv) * Crow;

  f32x16 acc[2];
#pragma unroll
  for (int i = 0; i < 16; ++i) { acc[0][i] = 0.f; acc[1][i] = 0.f; }

  const int ml = wave * 32 + (lane & 31);
  const int my = ml >> 3, mx = ml & 7;
  const int koffs = (lane >> 5) << 3;
  const int hpbase = my * HALO_W + mx;

  int4 rA[NSLOT];
  int4 rB0[2], rB1[2];

  auto loadA = [&](int cc2, int4* r) {
    int kb = cc2 << 6;
#pragma unroll
    for (int s = 0; s < NSLOT; ++s) {
      int idx = s * 256 + tid;
      int4 v = make_int4(0, 0, 0, 0);
      int pos = idx >> 3, part = idx & 7;
      int hy = pos >> 3, hx = pos & 7;
      int gy = py0 + hy, gx = px0 + hx;
      int ch = kb + (part << 3);
      if ((unsigned)gy < (unsigned)H && (unsigned)gx < (unsigned)W && ch < Crow)
        v = *(const int4*)(src + srcb + (size_t)((gy << lgWv) + gx) * Crow + ch);
      r[s] = v;
    }
  };
  auto writeA = [&](const int4* r) {
#pragma unroll
    for (int s = 0; s < NSLOT; ++s) {
      int idx = s * 256 + tid;
      int pos = idx >> 3, part = idx & 7;
      u16* d = As + pos * APAD + (part << 3);
      *(int2*)d = make_int2(r[s].x, r[s].y);
      *(int2*)(d + 4) = make_int2(r[s].z, r[s].w);
    }
  };
  auto loadB = [&](int j, int4* r) {
    const u16* wsrc = wT + (((size_t)j * Cpadv + nt) << 6);
    r[0] = *(const int4*)(wsrc + ((tid >> 3) << 6) + ((tid & 7) << 3));
    r[1] = *(const int4*)(wsrc + (((tid >> 3) + 32) << 6) + ((tid & 7) << 3));
  };
  auto writeB = [&](int bufi, const int4* r) {
    u16* bb = Bs[bufi];
    u16* d0 = bb + (tid >> 3) * APAD + ((tid & 7) << 3);
    u16* d1 = bb + ((tid >> 3) + 32) * APAD + ((tid & 7) << 3);
    *(int2*)d0 = make_int2(r[0].x, r[0].y);
    *(int2*)(d0 + 4) = make_int2(r[0].z, r[0].w);
    *(int2*)d1 = make_int2(r[1].x, r[1].y);
    *(int2*)(d1 + 4) = make_int2(r[1].z, r[1].w);
  };

  loadA(0, rA);
  loadB(0, rB0);
  if (ktot > 1) loadB(1, rB1);
  writeA(rA);
  writeB(0, rB0);
  if (ktot > 2) loadB(2, rB0);
  if (NCv > 1) loadA(1, rA);
  __syncthreads();

  int kk = 0, cc = 0;
  while (true) {
    TAPX(rB1);
    if (kk >= ktot) break;
    TAPX(rB0);
    if (kk >= ktot) break;
  }

  const int col = lane & 31;
  const int rbs = 4 * (lane >> 5);
  const float bv0 = bias[nt + 2 * col];
  const float bv1 = bias[nt + 2 * col + 1];
#pragma unroll
  for (int r = 0; r < 16; ++r) {
    int m2 = wave * 32 + rbs + (r & 3) + 8 * (r >> 2);
    int posi = ((py0 + (m2 >> 3)) << lgWv) + px0 + (m2 & 7);
    float v0 = acc[0][r] + bv0;
    float v1 = acc[1][r] + bv1;
    unsigned pk = (unsigned)f2bf(v0) | ((unsigned)f2bf(v1) << 16);
    *(unsigned*)((u16*)dstv + ((size_t)(batch << lgHWv) + posi) * 256 + nt + 2 * col) = pk;
  }
}

// ---------------- 3x3 conv: r12/r14 exact (b64 ld8, APAD 68, 3-slot B-ring) ----------------
#define TAP9(T, S) do {                                                        \
    constexpr int hpo_ = ((T) / 3 - 1) * 10 + ((T) % 3 - 1);                   \
    const u16* ar = As + (hpbase + hpo_) * APAD + koffs;                       \
    const u16* br0 = Bs[S] + (lane & 31) * APAD + koffs;                       \
    const u16* br1 = br0 + 32 * APAD;                                          \
    _Pragma("unroll")                                                          \
    for (int ks = 0; ks < 4; ++ks) {                                           \
      bf16x8 af = ld8(ar + ks * 16);                                           \
      acc[0] = __builtin_amdgcn_mfma_f32_32x32x16_bf16(af, ld8(br0 + ks * 16), acc[0], 0, 0, 0); \
      acc[1] = __builtin_amdgcn_mfma_f32_32x32x16_bf16(af, ld8(br1 + ks * 16), acc[1], 0, 0, 0); \
    }                                                                          \
  } while (0)

__global__ __launch_bounds__(256, 3) void conv9_kernel(ConvP p) {
  constexpr int HALO_W = 10;
  constexpr int NA = 18 * 10 * 8;            // 1440
  constexpr int NSLOT = 6;
  __shared__ u16 As[180 * APAD];             // 23.9 KB
  __shared__ u16 Bs[3][64 * APAD];           // 25.5 KB -> total 49.4 KB, 3 blocks/CU
  const int tid = threadIdx.x;
  const int br = blockIdx.z;
  if (blockIdx.y >= p.ny[br]) return;
  const int bx = blockIdx.x;
  const int lv = (bx >= p.pre[1]) + (bx >= p.pre[2]);
  const u16* __restrict__ src = p.src[br][lv];
  const u16* __restrict__ wT = p.wT[br][lv];
  const float* bias = p.bias[br][lv];
  void* dstv = p.dst[br][lv];
  const int H = p.H[lv], W = p.W[lv];
  const int lgWv = p.lgW[lv], lgHWv = p.lgHW[lv];
  const int Crow = p.Crow[lv];
  const int Cpadv = p.Cpad[br];
  const int nt = blockIdx.y * 64;
  const int wave = tid >> 6, lane = tid & 63;

  const int pidx = bx - p.pre[lv];
  const int lgppb = lgHWv - 7;
  const int lgnpx = lgWv - 3;
  const int batch = pidx >> lgppb;
  const int pp = pidx & ((1 << lgppb) - 1);
  const int py0 = (pp >> lgnpx) << 4;
  const int px0 = (pp & ((1 << lgnpx) - 1)) << 3;
  const size_t srcb = (size_t)batch * (1 << lgHWv) * Crow;

  f32x16 acc[2];
#pragma unroll
  for (int i = 0; i < 16; ++i) { acc[0][i] = 0.f; acc[1][i] = 0.f; }

  const int ml = wave * 32 + (lane & 31);
  const int my = ml >> 3, mx = ml & 7;
  const int koffs = (lane >> 5) << 3;
  const int hpbase = (my + 1) * HALO_W + (mx + 1);

  int4 rA[NSLOT];
  int4 rB[6];                                // 3 slots x 2 int4, constant-indexed

  auto loadA = [&](int cc2, int4* r) {
    int kb = cc2 << 6;
#pragma unroll
    for (int s = 0; s < NSLOT; ++s) {
      int idx = s * 256 + tid;
      int4 v = make_int4(0, 0, 0, 0);
      if (idx < NA) {
        int pos = idx >> 3, part = idx & 7;
        int hy = pos / HALO_W, hx = pos - hy * HALO_W;
        int gy = py0 + hy - 1, gx = px0 + hx - 1;
        int ch = kb + (part << 3);
        if ((unsigned)gy < (unsigned)H && (unsigned)gx < (unsigned)W && ch < Crow)
          v = *(const int4*)(src + srcb + (size_t)((gy << lgWv) + gx) * Crow + ch);
      }
      r[s] = v;
    }
  };
  auto writeA = [&](const int4* r) {
#pragma unroll
    for (int s = 0; s < NSLOT; ++s) {
      int idx = s * 256 + tid;
      if (idx < NA) {
        int pos = idx >> 3, part = idx & 7;
        u16* d = As + pos * APAD + (part << 3);
        *(int2*)d = make_int2(r[s].x, r[s].y);
        *(int2*)(d + 4) = make_int2(r[s].z, r[s].w);
      }
    }
  };
  auto loadB3 = [&](int j, int4* r) {        // loads kk = j, j+1, j+2
#pragma unroll
    for (int s = 0; s < 3; ++s) {
      const u16* wsrc = wT + (((size_t)(j + s) * Cpadv + nt) << 6);
      r[2 * s] = *(const int4*)(wsrc + ((tid >> 3) << 6) + ((tid & 7) << 3));
      r[2 * s + 1] = *(const int4*)(wsrc + (((tid >> 3) + 32) << 6) + ((tid & 7) << 3));
    }
  };
  auto writeB3 = [&](const int4* r) {        // stores slots 0,1,2
#pragma unroll
    for (int s = 0; s < 3; ++s) {
      u16* bb = Bs[s];
      u16* d0 = bb + (tid >> 3) * APAD + ((tid & 7) << 3);
      u16* d1 = bb + ((tid >> 3) + 32) * APAD + ((tid & 7) << 3);
      *(int2*)d0 = make_int2(r[2 * s].x, r[2 * s].y);
      *(int2*)(d0 + 4) = make_int2(r[2 * s].z, r[2 * s].w);
      *(int2*)d1 = make_int2(r[2 * s + 1].x, r[2 * s + 1].y);
      *(int2*)(d1 + 4) = make_int2(r[2 * s + 1].z, r[2 * s + 1].w);
    }
  };

  // prologue: slots <- kk 0..2; rB <- kk 3..5; As <- chunk0; rA <- chunk1
  loadA(0, rA);
  loadB3(0, rB);
  writeA(rA);
  writeB3(rB);
  loadB3(3, rB);
  loadA(1, rA);
  __syncthreads();

  for (int cc = 0; cc < 4; ++cc) {
    TAP9(0, 0); TAP9(1, 1); TAP9(2, 2);
    __syncthreads();                         // vmcnt drain: rB loads are 3 taps old
    writeB3(rB);                             // slots <- 9cc+3..5
    __syncthreads();
    loadB3(cc * 9 + 6, rB);
    TAP9(3, 0); TAP9(4, 1); TAP9(5, 2);
    __syncthreads();
    writeB3(rB);                             // slots <- 9cc+6..8
    __syncthreads();
    if (cc * 9 + 9 < 36) loadB3(cc * 9 + 9, rB);
    TAP9(6, 0); TAP9(7, 1); TAP9(8, 2);
    __syncthreads();
    if (cc < 3) {
      writeB3(rB);                           // slots <- 9(cc+1)+0..2
      writeA(rA);                            // As <- chunk cc+1
      __syncthreads();
      loadB3(cc * 9 + 12, rB);
      if (cc < 2) loadA(cc + 2, rA);
    }
  }

  // epilogue: C/D layout col=lane&31, row=(reg&3)+8*(reg>>2)+4*(lane>>5).
  // acc[f] col c = logical channel nt + 2c + f (pairN weights) -> packed dword store.
  const int col = lane & 31;
  const int rbs = 4 * (lane >> 5);
  const int nbase = nt + 2 * col;
  const float bv0 = bias[nbase];
  const float bv1 = bias[nbase + 1];
#pragma unroll
  for (int r = 0; r < 16; ++r) {
    int m2 = wave * 32 + rbs + (r & 3) + 8 * (r >> 2);
    int posi = ((py0 + (m2 >> 3)) << lgWv) + px0 + (m2 & 7);
    float v0 = acc[0][r] + bv0;
    float v1 = acc[1][r] + bv1;
    if (p.relu) { v0 = fmaxf(v0, 0.f); v1 = fmaxf(v1, 0.f); }
    if (!p.direct) {
      unsigned pk = (unsigned)f2bf(v0) | ((unsigned)f2bf(v1) << 16);
      *(unsigned*)((u16*)dstv + ((size_t)(batch << lgHWv) + posi) * 256 + nbase) = pk;
    } else {
      float* dd = (float*)dstv + ((size_t)(batch * 5376 + p.locoff[lv] + posi)) * 85 + p.choff[br];
      if (nbase < p.Nvalid[br]) dd[nbase] = v0;
      if (nbase + 1 < p.Nvalid[br]) dd[nbase + 1] = v1;
    }
  }
}

// ---------------- host ----------------
extern "C" void kernel_launch(void* const* d_in, const int* in_sizes, int n_in,
                              void* d_out, int out_size, void* d_ws, size_t ws_size,
                              hipStream_t stream) {
  (void)in_sizes; (void)n_in; (void)out_size; (void)ws_size;
  const float* c3 = (const float*)d_in[0];
  const float* c4 = (const float*)d_in[1];
  const float* c5 = (const float*)d_in[2];
  const float* lat_w[3] = {(const float*)d_in[3], (const float*)d_in[7], (const float*)d_in[11]};
  const float* lat_b[3] = {(const float*)d_in[4], (const float*)d_in[8], (const float*)d_in[12]};
  const float* out_w[3] = {(const float*)d_in[5], (const float*)d_in[9], (const float*)d_in[13]};
  const float* out_b[3] = {(const float*)d_in[6], (const float*)d_in[10], (const float*)d_in[14]};
  const float* scw = (const float*)d_in[15];
  const float* scb = (const float*)d_in[16];
  const float* sbw = (const float*)d_in[17];
  const float* sbb = (const float*)d_in[18];
  const float* clsw = (const float*)d_in[19];
  const float* clsb = (const float*)d_in[20];
  const float* boxw = (const float*)d_in[21];
  const float* boxb = (const float*)d_in[22];
  const float* ctrw = (const float*)d_in[23];
  const float* ctrb = (const float*)d_in[24];
  float* out = (float*)d_out;
  u16* ws = (u16*)d_ws;

  size_t o = 0;
  auto alloc = [&](size_t n) { size_t r = o; o += (n + 127) & ~(size_t)127; return ws + r; };

  u16* c3t = alloc(524288);
  u16* c4t = alloc(327680);
  u16* c5t = alloc(204800);
  u16* l3 = alloc(2097152);
  u16* l4 = alloc(524288);
  u16* l4n = alloc(524288);
  u16* l5 = alloc(131072);
  u16* p3 = alloc(2097152);
  u16* p4 = alloc(524288);
  u16* p5 = alloc(131072);
  const size_t hsz[3] = {2097152, 524288, 131072};
  u16 *hc[2][3], *hb[2][3];
  for (int ab = 0; ab < 2; ++ab)
    for (int lvv = 0; lvv < 3; ++lvv) { hc[ab][lvv] = alloc(hsz[lvv]); hb[ab][lvv] = alloc(hsz[lvv]); }
  const int latCin[3] = {64, 160, 400};
  const int latNC[3] = {1, 3, 7};
  u16* wl[3]; for (int i = 0; i < 3; ++i) wl[i] = alloc((size_t)latNC[i] * 256 * 64);
  u16* wo[3]; for (int i = 0; i < 3; ++i) wo[i] = alloc(589824);
  u16* wsc[4]; for (int i = 0; i < 4; ++i) wsc[i] = alloc(589824);
  u16* wsb[4]; for (int i = 0; i < 4; ++i) wsb[i] = alloc(589824);
  u16* wcls = alloc(294912);
  u16* wbc = alloc(147456);
  float* bcls = (float*)alloc(256);
  float* bbc = (float*)alloc(128);
  alloc(2048);  // guard

  // ---- prep: weight transforms + input transpose (merged) ----
  WArgs wa;
  int ji = 0;
  for (int i = 0; i < 3; ++i) wa.j[ji++] = WJob{lat_w[i], wl[i], latCin[i], 256, 1, latNC[i], 256, 0};
  for (int i = 0; i < 3; ++i) wa.j[ji++] = WJob{out_w[i], wo[i], 256, 256, 9, 4, 256, 0};
  for (int i = 0; i < 4; ++i) wa.j[ji++] = WJob{scw + (size_t)i * 589824, wsc[i], 256, 256, 9, 4, 256, 0};
  for (int i = 0; i < 4; ++i) wa.j[ji++] = WJob{sbw + (size_t)i * 589824, wsb[i], 256, 256, 9, 4, 256, 0};
  wa.j[ji++] = WJob{clsw, wcls, 256, 80, 9, 4, 128, 0};
  wa.j[ji++] = WJob{nullptr, wbc, 256, 5, 9, 4, 64, 1};
  wa.box_w = boxw; wa.ctr_w = ctrw;
  wa.cls_b = clsb; wa.box_b = boxb; wa.ctr_b = ctrb; wa.bcls = bcls; wa.bbc = bbc;
  wa.tc3 = c3; wa.tc4 = c4; wa.tc5 = c5;
  wa.tc3t = c3t; wa.tc4t = c4t; wa.tc5t = c5t;
  prep_kernel<<<dim3(256, 17), dim3(256), 0, stream>>>(wa);

  const int Hs[3] = {64, 32, 16};
  const int lgWs[3] = {6, 5, 4}, lgHWs[3] = {12, 10, 8};
  auto setLv = [&](ConvP& p, int i, int lvv) {
    p.H[i] = Hs[lvv]; p.W[i] = Hs[lvv]; p.lgW[i] = lgWs[lvv]; p.lgHW[i] = lgHWs[lvv];
  };

  // ---- lateral 1x1 convs (all levels fused) ----
  {
    ConvP p{};
    const u16* srcs[3] = {c3t, c4t, c5t};
    u16* dsts[3] = {l3, l4, l5};
    for (int i = 0; i < 3; ++i) {
      p.src[0][i] = srcs[i]; p.wT[0][i] = wl[i]; p.bias[0][i] = lat_b[i]; p.dst[0][i] = dsts[i];
      setLv(p, i, i);
      p.NC[i] = latNC[i]; p.Crow[i] = latCin[i]; p.locoff[i] = 0;
    }
    p.pre[0] = 0; p.pre[1] = 64; p.pre[2] = 80;
    p.Cpad[0] = 256; p.Nvalid[0] = 0; p.choff[0] = 0; p.ny[0] = 4;
    p.relu = 0; p.direct = 0;
    conv1_kernel<<<dim3(84, 4, 1), dim3(256), 0, stream>>>(p);
  }

  // ---- fused upsample-adds (vectorized) ----
  upadd2_kernel<<<dim3(1280), dim3(256), 0, stream>>>(l3, l4n, l4, l5);

  // ---- FPN out convs (all levels fused) ----
  {
    ConvP p{};
    const u16* srcs[3] = {l3, l4n, l5};
    u16* dsts[3] = {p3, p4, p5};
    for (int i = 0; i < 3; ++i) {
      p.src[0][i] = srcs[i]; p.wT[0][i] = wo[i]; p.bias[0][i] = out_b[i]; p.dst[0][i] = dsts[i];
      setLv(p, i, i);
      p.NC[i] = 4; p.Crow[i] = 256; p.locoff[i] = 0;
    }
    p.pre[0] = 0; p.pre[1] = 64; p.pre[2] = 80;
    p.Cpad[0] = 256; p.Nvalid[0] = 0; p.choff[0] = 0; p.ny[0] = 4;
    p.relu = 0; p.direct = 0;
    conv9_kernel<<<dim3(84, 4, 1), dim3(256), 0, stream>>>(p);
  }

  // ---- stem layers: all levels + both branches fused per layer ----
  u16* pin[3] = {p3, p4, p5};
  for (int i = 0; i < 4; ++i) {
    ConvP p{};
    int di = i & 1;
    for (int lvv = 0; lvv < 3; ++lvv) {
      const u16 *s0, *s1;
      if (i == 0) { s0 = pin[lvv]; s1 = pin[lvv]; }
      else { int si = (i - 1) & 1; s0 = hc[si][lvv]; s1 = hb[si][lvv]; }
      p.src[0][lvv] = s0; p.src[1][lvv] = s1;
      p.wT[0][lvv] = wsc[i]; p.wT[1][lvv] = wsb[i];
      p.bias[0][lvv] = scb + i * 256; p.bias[1][lvv] = sbb + i * 256;
      p.dst[0][lvv] = hc[di][lvv]; p.dst[1][lvv] = hb[di][lvv];
      setLv(p, lvv, lvv);
      p.NC[lvv] = 4; p.Crow[lvv] = 256; p.locoff[lvv] = 0;
    }
    p.pre[0] = 0; p.pre[1] = 64; p.pre[2] = 80;
    p.Cpad[0] = 256; p.Cpad[1] = 256;
    p.Nvalid[0] = 0; p.Nvalid[1] = 0; p.choff[0] = 0; p.choff[1] = 0;
    p.ny[0] = 4; p.ny[1] = 4;
    p.relu = 1; p.direct = 0;
    conv9_kernel<<<dim3(84, 4, 2), dim3(256), 0, stream>>>(p);
  }

  // ---- fused finals: z=0 cls (80ch), z=1 box+ctr (5ch), f32 (B,5376,85) ----
  {
    const int locoffs[3] = {0, 4096, 5120};
    ConvP p{};
    for (int lvv = 0; lvv < 3; ++lvv) {
      p.src[0][lvv] = hc[1][lvv]; p.wT[0][lvv] = wcls; p.bias[0][lvv] = bcls; p.dst[0][lvv] = out;
      p.src[1][lvv] = hb[1][lvv]; p.wT[1][lvv] = wbc; p.bias[1][lvv] = bbc; p.dst[1][lvv] = out;
      setLv(p, lvv, lvv);
      p.NC[lvv] = 4; p.Crow[lvv] = 256; p.locoff[lvv] = locoffs[lvv];
    }
    p.pre[0] = 0; p.pre[1] = 64; p.pre[2] = 80;
    p.Cpad[0] = 128; p.Cpad[1] = 64;
    p.Nvalid[0] = 80; p.Nvalid[1] = 5;
    p.choff[0] = 0; p.choff[1] = 80;
    p.ny[0] = 2; p.ny[1] = 1;
    p.relu = 0; p.direct = 1;
    conv9_kernel<<<dim3(84, 2, 2), dim3(256), 0, stream>>>(p);
  }
}